// Round 17
// baseline (570.677 us; speedup 1.0000x reference)
//
#include <hip/hip_runtime.h>
#include <cstdint>
#include <cstddef>

// Problem constants (R,1,C) x, t, (K,C) A, (T,) bar_alpha
#define R_DIM 4096
#define K_DIM 16384
#define C_DIM 512
#define SPLITS 4                 // split over the 16384 k-dimension
#define BM 32                    // rows per workgroup (r10 halved)
#define BK 128                   // k-tile
#define KRANGE (K_DIM / SPLITS)  // 4096
#define NTILES (KRANGE / BK)     // 32
#define GTILES (K_DIM / BK)      // 128 global tiles
#define ACH 16384                // A-chunk bytes ([128k][32c] hi 8K + lo 8K)

typedef unsigned short us8 __attribute__((ext_vector_type(8)));
typedef float f32x4 __attribute__((ext_vector_type(4)));
typedef __bf16 bfv8 __attribute__((ext_vector_type(8)));

#define MFMA16(a, b, c) __builtin_amdgcn_mfma_f32_16x16x32_bf16((a), (b), (c), 0, 0, 0)
#define BC(v) __builtin_bit_cast(bfv8, (v))

__device__ __forceinline__ unsigned short f2bf(float v) {
    union { float f; unsigned u; } x; x.f = v;
    unsigned r = x.u + 0x7fffu + ((x.u >> 16) & 1u);  // RNE
    return (unsigned short)(r >> 16);
}
__device__ __forceinline__ float bf2f(unsigned short b) {
    union { unsigned u; float f; } x; x.u = ((unsigned)b) << 16;
    return x.f;
}

__device__ __forceinline__ void gload16(const char* g, char* l) {
    __builtin_amdgcn_global_load_lds(
        (const __attribute__((address_space(1))) void*)g,
        (__attribute__((address_space(3))) void*)l, 16, 0, 0);
}

// Counted-vmcnt phase barrier (r10-proven): N = vmem items issued THIS phase;
// waiting to N drains everything older (incl. previous phase's stage) while
// leaving this phase's issues in flight.
#define PHASE_BAR(N) do {                                                   \
    asm volatile("s_waitcnt vmcnt(" #N ") lgkmcnt(0)" ::: "memory");        \
    __builtin_amdgcn_s_barrier();                                           \
    __builtin_amdgcn_sched_barrier(0);                                      \
} while (0)

// ---------------- workspace layout (bytes) ----------------
#define OFF_IMGA ((size_t)0)          // [GTILES][16][16384]  32 MB  A-chunk images
#define OFF_IMGC ((size_t)33554432)   // [GTILES][8][32768]   32 MB  C-chunk images
#define OFF_XH   ((size_t)67108864)   // [R][C] bf16 hi    4 MB
#define OFF_XL   ((size_t)71303168)   // [R][C] bf16 lo    4 MB
#define OFF_ASQ  ((size_t)75497472)   // [K] f32          64 KB
#define OFF_ROWP ((size_t)75563008)   // [R] float4       64 KB  {sa, 0.5*sa*sa, inv*log2e, inv}
#define OFF_PO   ((size_t)75628544)   // [R][SPLITS][C] f32  32 MB
#define OFF_PM   ((size_t)109182976)  // [R][SPLITS] f32  64 KB
#define OFF_PL   ((size_t)109248512)  // [R][SPLITS] f32  64 KB
#define WS_NEED  ((size_t)109314048)

// ---------------- LDS layout (bytes) — 64 KB total -> 2 blocks/CU ----------------
#define SM_U    49152    // u hi [32m][128k] bf16 swizzled  8 KB
#define SM_U2   57344    // u lo                            8 KB
#define SM_TOT  65536
// staging buffers at 0 / 16384 / 32768; softmax exchange lives in the dead
// staging buffer during Phase B (smax at +0, ssum at +256).

// ======================= prep kernels =======================

__global__ void k_rows(const int* __restrict__ t, const float* __restrict__ bar_alpha,
                       float4* __restrict__ rowp) {
    int r = blockIdx.x * 256 + threadIdx.x;
    if (r >= R_DIM) return;
    float ba = bar_alpha[t[r]];
    float sa = sqrtf(ba);
    float inv = 1.0f / (1.0f - ba);
    rowp[r] = make_float4(sa, 0.5f * sa * sa, inv * 1.4426950408889634f, inv);
}

__global__ void k_splitx(const float* __restrict__ x, us8* __restrict__ xh, us8* __restrict__ xl) {
    int i = blockIdx.x * 256 + threadIdx.x;   // group of 8 elements
    if (i >= R_DIM * C_DIM / 8) return;
    const float4* x4 = (const float4*)x + (size_t)i * 2;
    float v[8];
    float4 a = x4[0], b = x4[1];
    v[0]=a.x; v[1]=a.y; v[2]=a.z; v[3]=a.w; v[4]=b.x; v[5]=b.y; v[6]=b.z; v[7]=b.w;
    us8 h, l;
#pragma unroll
    for (int j = 0; j < 8; ++j) {
        unsigned short hb = f2bf(v[j]);
        h[j] = hb;
        l[j] = f2bf(v[j] - bf2f(hb));
    }
    xh[i] = h; xl[i] = l;
}

// A-chunk images, 16 KB each: block = gt*16 + jc (c-range jc*32..+31).
// SWIZZLE FIX (r13 disease): pos = kl*64 + ((cb ^ (kl&3)) << 4).
// Read pattern row*64 + slot*16 over 16 consecutive rows had banks
// 16*row+4*slot mod 32 = 2 values (8-way conflict); XOR-ing slot with row&3
// spreads to 8 start positions -> 2 lanes/bank = free (m136).
// hi at pos, lo at pos+8192.
__global__ __launch_bounds__(256) void k_imgA(const float* __restrict__ A, char* __restrict__ img) {
    int gt = blockIdx.x >> 4, jc = blockIdx.x & 15;
    char* base = img + (size_t)blockIdx.x * ACH;
    int t = threadIdx.x;
#pragma unroll
    for (int it = 0; it < 2; ++it) {
        int p = t + it * 256;
        int kl = p >> 2, cb = p & 3;
        const float* src = A + (size_t)(gt * 128 + kl) * C_DIM + jc * 32 + cb * 8;
        us8 h, l;
#pragma unroll
        for (int q = 0; q < 8; ++q) {
            float v = src[q];
            unsigned short hb = f2bf(v);
            h[q] = hb; l[q] = f2bf(v - bf2f(hb));
        }
        int pos = kl * 64 + ((cb ^ (kl & 3)) << 4);
        *(us8*)(base + pos) = h;
        *(us8*)(base + 8192 + pos) = l;
    }
}

// C-chunk images (transposed, unchanged r10 format): pos = cl*256 + ((kb*16) ^ ((cl&7)<<4))
__global__ __launch_bounds__(256) void k_imgC(const float* __restrict__ A, char* __restrict__ img) {
    int gt = blockIdx.x >> 3, j = blockIdx.x & 7;
    char* base = img + (size_t)blockIdx.x * 32768;
    int t = threadIdx.x;
#pragma unroll
    for (int it = 0; it < 4; ++it) {
        int p = t + it * 256;
        int cl = p & 63, kb = p >> 6;
        us8 h, l;
#pragma unroll
        for (int q = 0; q < 8; ++q) {
            float v = A[(size_t)(gt * 128 + kb * 8 + q) * C_DIM + j * 64 + cl];
            unsigned short hb = f2bf(v);
            h[q] = hb; l[q] = f2bf(v - bf2f(hb));
        }
        int pos = cl * 256 + ((kb * 16) ^ ((cl & 7) << 4));
        *(us8*)(base + pos) = h;
        *(us8*)(base + 16384 + pos) = l;
    }
}

__global__ void k_asq(const float* __restrict__ A, float* __restrict__ Asq) {
    int wid = threadIdx.x >> 6, lane = threadIdx.x & 63;
    int k = blockIdx.x * 4 + wid;
    const float4* a4 = (const float4*)(A + (size_t)k * C_DIM);
    float s = 0.f;
#pragma unroll
    for (int j = 0; j < 2; ++j) {
        float4 v = a4[lane * 2 + j];
        s += v.x * v.x + v.y * v.y + v.z * v.z + v.w * v.w;
    }
#pragma unroll
    for (int off = 32; off; off >>= 1) s += __shfl_xor(s, off);
    if (lane == 0) Asq[k] = s;
}

// ======================= fused flash-style kernel =======================
// r13 (BM=32, 256 thr, 4 waves = 2wr x 2wc, 64 KB LDS -> 2 blocks/CU,
// decoupled barrier domains) with the A-image bank-conflict FIX.
// grid=512; XCD=b%8 -> split=b&3 (one stream/XCD, 64 sharers); x/XCD = 4 MB;
// x line-dup 2; B-frag dup 2. 3x16KB staging, counted-vmcnt 2-ahead.
__global__ __launch_bounds__(256, 2) void k_fused(
    const char* __restrict__ imgA, const char* __restrict__ imgC,
    const unsigned short* __restrict__ xh, const unsigned short* __restrict__ xl,
    const float* __restrict__ Asq, const float4* __restrict__ rowp,
    float* __restrict__ pO, float* __restrict__ pM, float* __restrict__ pL)
{
    extern __shared__ char smem[];
    const int tid = threadIdx.x;
    const int lane = tid & 63, wid = tid >> 6;
    const int wr = wid >> 1, wc = wid & 1;
    const int l15 = lane & 15, l4 = lane >> 4;
    const int rb = (blockIdx.x >> 2) * BM;
    const int split = blockIdx.x & (SPLITS - 1);

    float sa[4], hb[4], ce[4];
#pragma unroll
    for (int q = 0; q < 4; ++q) {
        float4 p = rowp[rb + wr * 16 + l4 * 4 + q];
        sa[q] = p.x; hb[q] = p.y; ce[q] = p.z;
    }
    float Mr[4], Lr[4];
#pragma unroll
    for (int q = 0; q < 4; ++q) { Mr[q] = -1e30f; Lr[q] = 0.f; }
    f32x4 of[8][2];   // [c-chunk j][f2]
#pragma unroll
    for (int a = 0; a < 8; ++a)
#pragma unroll
        for (int b = 0; b < 2; ++b) of[a][b] = (f32x4){0.f, 0.f, 0.f, 0.f};

    const int xrow = (rb + wr * 16 + l15) * C_DIM;
    const int stg = tid * 16;   // 0..4080

    // prologue: A0->BUF0, A1->BUF1, drain.
    {
        const char* s0 = imgA + (size_t)(split * NTILES) * 16 * ACH;
        const char* s1 = s0 + ACH;
#pragma unroll
        for (int i = 0; i < 4; ++i) gload16(s0 + stg + i * 4096, smem + stg + i * 4096);
#pragma unroll
        for (int i = 0; i < 4; ++i) gload16(s1 + stg + i * 4096, smem + ACH + stg + i * 4096);
    }
    __syncthreads();
    int cur = 0;

    for (int kt = 0; kt < NTILES; ++kt) {
        const int gt = split * NTILES + kt;
        const int gtn = (kt == NTILES - 1) ? split * NTILES : gt + 1;  // wrapped
        const int kbase = gt * BK;
        f32x4 sf[4];
#pragma unroll
        for (int f = 0; f < 4; ++f) sf[f] = (f32x4){0.f, 0.f, 0.f, 0.f};

        // ---------- Phase A: S[32m][128k], 16 chunks of 32 c ----------
        us8 xbh[2], xbl[2];
#pragma unroll
        for (int jc = 0; jc < 16; ++jc) {
            // x loads first (issue order: x before stage -> compiler x-waits
            // don't drain the stage)
            if (jc == 0) {
                xbh[0] = *(const us8*)(xh + xrow + l4 * 8);
                xbl[0] = *(const us8*)(xl + xrow + l4 * 8);
            }
            if (jc < 15) {
                int off = xrow + (jc + 1) * 32 + l4 * 8;
                xbh[(jc + 1) & 1] = *(const us8*)(xh + off);
                xbl[(jc + 1) & 1] = *(const us8*)(xl + off);
            }
            {   // stage 2 phases ahead into buf[(cur+2)%3]
                char* d = smem + ((cur + 2) % 3) * ACH + stg;
                const char* s = (jc < 14)
                    ? imgA + ((size_t)gt * 16 + jc + 2) * ACH
                    : imgC + ((size_t)gt * 8 + (jc - 14)) * 32768;  // C0/C1 hi-only
#pragma unroll
                for (int i = 0; i < 4; ++i) gload16(s + stg + i * 4096, d + i * 4096);
            }
            const char* B = smem + cur * ACH;
#pragma unroll
            for (int f = 0; f < 4; ++f) {
                int row = wc * 64 + f * 16 + l15;          // k-index in tile
                int byte = row * 64 + ((l4 ^ (row & 3)) << 4);   // conflict-free read
                bfv8 qh = *(const bfv8*)(B + byte);
                bfv8 ql = *(const bfv8*)(B + 8192 + byte);
                sf[f] = MFMA16(BC(xbh[jc & 1]), qh, sf[f]);
                sf[f] = MFMA16(BC(xbh[jc & 1]), ql, sf[f]);
                sf[f] = MFMA16(BC(xbl[jc & 1]), qh, sf[f]);
            }
            if (jc == 0)      PHASE_BAR(8);   // cold2 + pref2 + stage4
            else if (jc < 15) PHASE_BAR(6);   // pref2 + stage4
            else              PHASE_BAR(4);   // stage4
            cur = (cur + 1) % 3;
        }

        // ---------- Phase B: online softmax (exchange in dead staging buffer) ----------
        {
            char* dead = smem + ((cur + 2) % 3) * ACH;
            float* smax = (float*)dead;            // [2][32]
            float* ssum = (float*)(dead + 256);    // [2][32]
            float g[4][4];
#pragma unroll
            for (int f = 0; f < 4; ++f) {
                float asq = Asq[kbase + wc * 64 + f * 16 + l15];
#pragma unroll
                for (int q = 0; q < 4; ++q) g[f][q] = sa[q] * sf[f][q] - hb[q] * asq;
            }
            float tmax[4];
#pragma unroll
            for (int q = 0; q < 4; ++q)
                tmax[q] = fmaxf(fmaxf(g[0][q], g[1][q]), fmaxf(g[2][q], g[3][q]));
#pragma unroll
            for (int off = 1; off < 16; off <<= 1)
#pragma unroll
                for (int q = 0; q < 4; ++q) tmax[q] = fmaxf(tmax[q], __shfl_xor(tmax[q], off));
            if (l15 == 0) {
#pragma unroll
                for (int q = 0; q < 4; ++q) smax[wc * 32 + wr * 16 + l4 * 4 + q] = tmax[q];
            }
            __syncthreads();   // #1 (drains C0/C1 stages too)
            float Mn[4], al[4];
#pragma unroll
            for (int q = 0; q < 4; ++q) {
                float other = smax[(wc ^ 1) * 32 + wr * 16 + l4 * 4 + q];
                float tm = fmaxf(tmax[q], other);
                Mn[q] = fmaxf(Mr[q], tm);
                al[q] = exp2f((Mr[q] - Mn[q]) * ce[q]);
            }
            float u[4][4], tsum[4] = {0.f, 0.f, 0.f, 0.f};
#pragma unroll
            for (int f = 0; f < 4; ++f)
#pragma unroll
                for (int q = 0; q < 4; ++q) {
                    u[f][q] = exp2f((g[f][q] - Mn[q]) * ce[q]);
                    tsum[q] += u[f][q];
                }
#pragma unroll
            for (int off = 1; off < 16; off <<= 1)
#pragma unroll
                for (int q = 0; q < 4; ++q) tsum[q] += __shfl_xor(tsum[q], off);
            if (l15 == 0) {
#pragma unroll
                for (int q = 0; q < 4; ++q) ssum[wc * 32 + wr * 16 + l4 * 4 + q] = tsum[q];
            }
            // write u (bf16 hi/lo) to LDS for GEMM2 A-operand
#pragma unroll
            for (int f = 0; f < 4; ++f)
#pragma unroll
                for (int q = 0; q < 4; ++q) {
                    int m_loc = wr * 16 + l4 * 4 + q;
                    int k_loc = wc * 64 + f * 16 + l15;
                    int byte = (m_loc * 256 + k_loc * 2) ^ ((m_loc & 7) << 4);
                    unsigned short uh = f2bf(u[f][q]);
                    *(unsigned short*)(smem + SM_U + byte) = uh;
                    *(unsigned short*)(smem + SM_U2 + byte) = f2bf(u[f][q] - bf2f(uh));
                }
            __syncthreads();   // #2
#pragma unroll
            for (int q = 0; q < 4; ++q) {
                float others = ssum[(wc ^ 1) * 32 + wr * 16 + l4 * 4 + q];
                Lr[q] = Lr[q] * al[q] + tsum[q] + others;
                Mr[q] = Mn[q];
            }
#pragma unroll
            for (int a = 0; a < 8; ++a)
#pragma unroll
                for (int b = 0; b < 2; ++b)
#pragma unroll
                    for (int q = 0; q < 4; ++q) of[a][b][q] *= al[q];
        }
        us8 uhf[4], ulf[4];
#pragma unroll
        for (int ks = 0; ks < 4; ++ks) {
            int m_loc = wr * 16 + l15;
            int byte = (m_loc * 256 + ks * 64 + l4 * 16) ^ ((m_loc & 7) << 4);
            uhf[ks] = *(const us8*)(smem + SM_U + byte);
            ulf[ks] = *(const us8*)(smem + SM_U2 + byte);
        }
        __syncthreads();   // #3: dead-buffer reads done before C j=0 stages into it

        // ---------- Phase C: O[32m][512c] += (uh+ul)*Ah, 8 chunks of 64 c ----------
#pragma unroll
        for (int j = 0; j < 8; ++j) {
            {   // stage 2 phases ahead
                char* d = smem + ((cur + 2) % 3) * ACH + stg;
                const char* s = (j < 6)
                    ? imgC + ((size_t)gt * 8 + j + 2) * 32768            // hi-only 16 KB
                    : imgA + ((size_t)gtn * 16 + (j - 6)) * ACH;          // next A0/A1
#pragma unroll
                for (int i = 0; i < 4; ++i) gload16(s + stg + i * 4096, d + i * 4096);
            }
            const char* B = smem + cur * ACH;
#pragma unroll
            for (int f2 = 0; f2 < 2; ++f2) {
                int cl = wc * 32 + f2 * 16 + l15;                        // c-row in chunk
#pragma unroll
                for (int ks = 0; ks < 4; ++ks) {
                    int byte = cl * 256 + ((ks * 64 + l4 * 16) ^ ((cl & 7) << 4));
                    bfv8 qh = *(const bfv8*)(B + byte);
                    of[j][f2] = MFMA16(BC(uhf[ks]), qh, of[j][f2]);
                    of[j][f2] = MFMA16(BC(ulf[ks]), qh, of[j][f2]);
                }
            }
            PHASE_BAR(4);   // stage4
            cur = (cur + 1) % 3;
        }
    }

    // ---------- write split partials ----------
#pragma unroll
    for (int j = 0; j < 8; ++j)
#pragma unroll
        for (int f2 = 0; f2 < 2; ++f2)
#pragma unroll
            for (int q = 0; q < 4; ++q) {
                int gm = rb + wr * 16 + l4 * 4 + q;
                int cg = j * 64 + wc * 32 + f2 * 16 + l15;
                pO[((size_t)gm * SPLITS + split) * C_DIM + cg] = of[j][f2][q];
            }
    if (wc == 0 && l15 == 0) {
#pragma unroll
        for (int q = 0; q < 4; ++q) {
            int gm = rb + wr * 16 + l4 * 4 + q;
            pM[gm * SPLITS + split] = Mr[q];
            pL[gm * SPLITS + split] = Lr[q];
        }
    }
}

// ======================= split-K combine =======================
__global__ void k_combine(const float* __restrict__ pO, const float* __restrict__ pM,
                          const float* __restrict__ pL, const float4* __restrict__ rowp,
                          float* __restrict__ out) {
    int r = blockIdx.x;
    int tid = threadIdx.x;   // 128 threads, 4 c's each
    float ce = rowp[r].z;
    float Ms[SPLITS], Ls[SPLITS];
    float M = -1e30f;
#pragma unroll
    for (int s = 0; s < SPLITS; ++s) {
        Ms[s] = pM[r * SPLITS + s];
        Ls[s] = pL[r * SPLITS + s];
        M = fmaxf(M, Ms[s]);
    }
    float es[SPLITS], L = 0.f;
#pragma unroll
    for (int s = 0; s < SPLITS; ++s) { es[s] = exp2f((Ms[s] - M) * ce); L += Ls[s] * es[s]; }
    float invL = 1.0f / L;
    f32x4 acc = (f32x4){0.f, 0.f, 0.f, 0.f};
#pragma unroll
    for (int s = 0; s < SPLITS; ++s) {
        f32x4 v = *(const f32x4*)(pO + ((size_t)r * SPLITS + s) * C_DIM + tid * 4);
        acc += v * es[s];
    }
    acc *= invL;
    *(f32x4*)(out + (size_t)r * C_DIM + tid * 4) = acc;
}

// ======================= launch =======================
extern "C" void kernel_launch(void* const* d_in, const int* in_sizes, int n_in,
                              void* d_out, int out_size, void* d_ws, size_t ws_size,
                              hipStream_t stream) {
    const float* x = (const float*)d_in[0];
    const int* t = (const int*)d_in[1];
    const float* A = (const float*)d_in[2];
    const float* bar_alpha = (const float*)d_in[3];
    float* out = (float*)d_out;
    char* ws = (char*)d_ws;
    if (ws_size < WS_NEED) return;

    char* imgA = ws + OFF_IMGA;
    char* imgC = ws + OFF_IMGC;
    unsigned short* Xh = (unsigned short*)(ws + OFF_XH);
    unsigned short* Xl = (unsigned short*)(ws + OFF_XL);
    float* Asq = (float*)(ws + OFF_ASQ);
    float4* rowp = (float4*)(ws + OFF_ROWP);
    float* pO = (float*)(ws + OFF_PO);
    float* pM = (float*)(ws + OFF_PM);
    float* pL = (float*)(ws + OFF_PL);

    (void)hipFuncSetAttribute((const void*)k_fused,
                              hipFuncAttributeMaxDynamicSharedMemorySize, SM_TOT);

    k_rows<<<R_DIM / 256, 256, 0, stream>>>(t, bar_alpha, rowp);
    k_splitx<<<(R_DIM * C_DIM / 8) / 256, 256, 0, stream>>>(x, (us8*)Xh, (us8*)Xl);
    k_imgA<<<GTILES * 16, 256, 0, stream>>>(A, imgA);
    k_imgC<<<GTILES * 8, 256, 0, stream>>>(A, imgC);
    k_asq<<<K_DIM / 4, 256, 0, stream>>>(A, Asq);
    k_fused<<<(R_DIM / BM) * SPLITS, 256, SM_TOT, stream>>>(imgA, imgC, Xh, Xl,
                                                            Asq, rowp, pO, pM, pL);
    k_combine<<<R_DIM, 128, 0, stream>>>(pO, pM, pL, rowp, out);
}

// Round 18
// 537.170 us; speedup vs baseline: 1.0624x; 1.0624x over previous
//
#include <hip/hip_runtime.h>
#include <cstdint>
#include <cstddef>

// Problem constants (R,1,C) x, t, (K,C) A, (T,) bar_alpha
#define R_DIM 4096
#define K_DIM 16384
#define C_DIM 512
#define SPLITS 4                 // split over the 16384 k-dimension
#define BM 64                    // rows per workgroup
#define BK 128                   // k-tile
#define KRANGE (K_DIM / SPLITS)  // 4096
#define NTILES (KRANGE / BK)     // 32
#define GTILES (K_DIM / BK)      // 128 global tiles

typedef unsigned short us8 __attribute__((ext_vector_type(8)));
typedef float f32x4 __attribute__((ext_vector_type(4)));
typedef __bf16 bfv8 __attribute__((ext_vector_type(8)));

#define MFMA16(a, b, c) __builtin_amdgcn_mfma_f32_16x16x32_bf16((a), (b), (c), 0, 0, 0)
#define BC(v) __builtin_bit_cast(bfv8, (v))

__device__ __forceinline__ unsigned short f2bf(float v) {
    union { float f; unsigned u; } x; x.f = v;
    unsigned r = x.u + 0x7fffu + ((x.u >> 16) & 1u);  // RNE
    return (unsigned short)(r >> 16);
}
__device__ __forceinline__ float bf2f(unsigned short b) {
    union { unsigned u; float f; } x; x.u = ((unsigned)b) << 16;
    return x.f;
}

// async global->LDS, 16B per lane.
__device__ __forceinline__ void gload16(const char* g, char* l) {
    __builtin_amdgcn_global_load_lds(
        (const __attribute__((address_space(1))) void*)g,
        (__attribute__((address_space(3))) void*)l, 16, 0, 0);
}

// Counted-vmcnt phase barrier: N = vmem items issued in the CURRENT phase.
// The stage that must land was issued in the PREVIOUS phase, so everything
// issued this phase comes after it in the in-order vmcnt queue -> waiting to
// depth N guarantees it completed, without draining this phase's issues.
#define PHASE_BAR(N) do {                                                   \
    asm volatile("s_waitcnt vmcnt(" #N ") lgkmcnt(0)" ::: "memory");        \
    __builtin_amdgcn_s_barrier();                                           \
    __builtin_amdgcn_sched_barrier(0);                                      \
} while (0)

// ---------------- workspace layout (bytes) ----------------
#define OFF_IMGA ((size_t)0)          // [GTILES][8][32768]  32 MB   [128k][64c] images
#define OFF_IMGC ((size_t)33554432)   // [GTILES][8][32768]  32 MB   [64c][128k] images
#define OFF_XH   ((size_t)67108864)   // [R][C] bf16 hi    4 MB
#define OFF_XL   ((size_t)71303168)   // [R][C] bf16 lo    4 MB
#define OFF_ASQ  ((size_t)75497472)   // [K] f32          64 KB
#define OFF_ROWP ((size_t)75563008)   // [R] float4       64 KB  {sa, 0.5*sa*sa, inv*log2e, inv}
#define OFF_PO   ((size_t)75628544)   // [R][SPLITS][C] f32  32 MB
#define OFF_PM   ((size_t)109182976)  // [R][SPLITS] f32  64 KB
#define OFF_PL   ((size_t)109248512)  // [R][SPLITS] f32  64 KB
#define WS_NEED  ((size_t)109314048)

// ---------------- LDS layout (bytes) ----------------
#define SM_BUF0 0        // staging buffers: 3 x 32 KB (hi 16K, lo 16K each)
#define SM_BUF1 32768
#define SM_BUF2 65536
#define SM_U    98304    // u hi [64m][128k] bf16 swizzled  16 KB
#define SM_U2   114688   // u lo                            16 KB
#define SM_MX   131072   // float[2][64] tile-max exchange 512 B
#define SM_SM   131584   // float[2][64] tile-sum exchange 512 B
#define SM_TOT  132096

// ======================= prep kernels (identical to round 8) =======================

__global__ void k_rows(const int* __restrict__ t, const float* __restrict__ bar_alpha,
                       float4* __restrict__ rowp) {
    int r = blockIdx.x * 256 + threadIdx.x;
    if (r >= R_DIM) return;
    float ba = bar_alpha[t[r]];
    float sa = sqrtf(ba);
    float inv = 1.0f / (1.0f - ba);
    rowp[r] = make_float4(sa, 0.5f * sa * sa, inv * 1.4426950408889634f, inv);
}

__global__ void k_splitx(const float* __restrict__ x, us8* __restrict__ xh, us8* __restrict__ xl) {
    int i = blockIdx.x * 256 + threadIdx.x;   // group of 8 elements
    if (i >= R_DIM * C_DIM / 8) return;
    const float4* x4 = (const float4*)x + (size_t)i * 2;
    float v[8];
    float4 a = x4[0], b = x4[1];
    v[0]=a.x; v[1]=a.y; v[2]=a.z; v[3]=a.w; v[4]=b.x; v[5]=b.y; v[6]=b.z; v[7]=b.w;
    us8 h, l;
#pragma unroll
    for (int j = 0; j < 8; ++j) {
        unsigned short hb = f2bf(v[j]);
        h[j] = hb;
        l[j] = f2bf(v[j] - bf2f(hb));
    }
    xh[i] = h; xl[i] = l;
}

// Phase-A chunk images: block = (gt, j). pos = kl*128 + ((cb*16) ^ ((kl&7)<<4))
__global__ __launch_bounds__(256) void k_imgA(const float* __restrict__ A, char* __restrict__ img) {
    int gt = blockIdx.x >> 3, j = blockIdx.x & 7;
    char* base = img + (size_t)blockIdx.x * 32768;
    int t = threadIdx.x;
#pragma unroll
    for (int it = 0; it < 4; ++it) {
        int p = t + it * 256;
        int kl = p >> 3, cb = p & 7;
        const float* src = A + (size_t)(gt * 128 + kl) * C_DIM + j * 64 + cb * 8;
        us8 h, l;
#pragma unroll
        for (int q = 0; q < 8; ++q) {
            float v = src[q];
            unsigned short hb = f2bf(v);
            h[q] = hb; l[q] = f2bf(v - bf2f(hb));
        }
        int pos = kl * 128 + ((cb * 16) ^ ((kl & 7) << 4));
        *(us8*)(base + pos) = h;
        *(us8*)(base + 16384 + pos) = l;
    }
}

// Phase-C chunk images (transposed): pos = cl*256 + ((kb*16) ^ ((cl&7)<<4))
__global__ __launch_bounds__(256) void k_imgC(const float* __restrict__ A, char* __restrict__ img) {
    int gt = blockIdx.x >> 3, j = blockIdx.x & 7;
    char* base = img + (size_t)blockIdx.x * 32768;
    int t = threadIdx.x;
#pragma unroll
    for (int it = 0; it < 4; ++it) {
        int p = t + it * 256;
        int cl = p & 63, kb = p >> 6;
        us8 h, l;
#pragma unroll
        for (int q = 0; q < 8; ++q) {
            float v = A[(size_t)(gt * 128 + kb * 8 + q) * C_DIM + j * 64 + cl];
            unsigned short hb = f2bf(v);
            h[q] = hb; l[q] = f2bf(v - bf2f(hb));
        }
        int pos = cl * 256 + ((kb * 16) ^ ((cl & 7) << 4));
        *(us8*)(base + pos) = h;
        *(us8*)(base + 16384 + pos) = l;
    }
}

__global__ void k_asq(const float* __restrict__ A, float* __restrict__ Asq) {
    int wid = threadIdx.x >> 6, lane = threadIdx.x & 63;
    int k = blockIdx.x * 4 + wid;
    const float4* a4 = (const float4*)(A + (size_t)k * C_DIM);
    float s = 0.f;
#pragma unroll
    for (int j = 0; j < 2; ++j) {
        float4 v = a4[lane * 2 + j];
        s += v.x * v.x + v.y * v.y + v.z * v.z + v.w * v.w;
    }
#pragma unroll
    for (int off = 32; off; off >>= 1) s += __shfl_xor(s, off);
    if (lane == 0) Asq[k] = s;
}

// ======================= fused flash-style kernel =======================
// Round-10 PROVEN OPTIMUM (537 us, FETCH 66 MB, absmax 0.03125), restored
// byte-for-byte (reproduced twice: r10 537, r16 538). 512 thr, topology
// split=b&3 rb=b>>2 (one stream/XCD, 32 sharers; x/XCD 4 MB L2-fit; x
// line-dup 2). Triple-buffered staging with counted-vmcnt barriers (loads
// stay in flight across barriers; never drain to 0 in the loop). 16x16x32
// engine, M_rep=1 (register-budget-proven). 2-term Phase C.
__global__ __launch_bounds__(512, 2) void k_fused(
    const char* __restrict__ imgA, const char* __restrict__ imgC,
    const unsigned short* __restrict__ xh, const unsigned short* __restrict__ xl,
    const float* __restrict__ Asq, const float4* __restrict__ rowp,
    float* __restrict__ pO, float* __restrict__ pM, float* __restrict__ pL)
{
    extern __shared__ char smem[];
    const int tid = threadIdx.x;
    const int lane = tid & 63, wid = tid >> 6;
    const int wr = wid >> 1, wc = wid & 1;
    const int l15 = lane & 15, l4 = lane >> 4;
    const int rb = (blockIdx.x >> 2) * BM;
    const int split = blockIdx.x & (SPLITS - 1);

    float sa[4], hb[4], ce[4];
#pragma unroll
    for (int q = 0; q < 4; ++q) {
        float4 p = rowp[rb + wr * 16 + l4 * 4 + q];
        sa[q] = p.x; hb[q] = p.y; ce[q] = p.z;
    }
    float Mr[4], Lr[4];
#pragma unroll
    for (int q = 0; q < 4; ++q) { Mr[q] = -1e30f; Lr[q] = 0.f; }
    f32x4 of[8][2];   // [c-chunk j][c-frag f]
#pragma unroll
    for (int a = 0; a < 8; ++a)
#pragma unroll
        for (int b = 0; b < 2; ++b) of[a][b] = (f32x4){0.f, 0.f, 0.f, 0.f};

    const int xrow = (rb + wr * 16 + l15) * C_DIM;
    const int stg = tid * 16;

    // prologue: stage A(tile0,chunk0)->BUF0 and A(tile0,chunk1)->BUF1, drain.
    {
        const char* s0 = imgA + (size_t)(split * NTILES) * 8 * 32768;
        const char* s1 = s0 + 32768;
#pragma unroll
        for (int i = 0; i < 4; ++i) gload16(s0 + stg + i * 8192, smem + SM_BUF0 + stg + i * 8192);
#pragma unroll
        for (int i = 0; i < 4; ++i) gload16(s1 + stg + i * 8192, smem + SM_BUF1 + stg + i * 8192);
    }
    __syncthreads();
    int cur = 0;   // buffer index read by the current phase

    for (int kt = 0; kt < NTILES; ++kt) {
        const int gt = split * NTILES + kt;
        const int gtn = (kt == NTILES - 1) ? split * NTILES : gt + 1;  // wrapped next tile
        const int kbase = gt * BK;
        f32x4 sf[4];
#pragma unroll
        for (int f = 0; f < 4; ++f) sf[f] = (f32x4){0.f, 0.f, 0.f, 0.f};

        // ---------- Phase A: S[64m][128k] = (xh+xl)(Ah+Al)^T, 8 chunks of 64 c ----------
        us8 xbh[2][2], xbl[2][2];
#pragma unroll
        for (int j = 0; j < 8; ++j) {
            // x loads first (so their compiler-wait doesn't force stage drain)
            if (j == 0) {
#pragma unroll
                for (int cs = 0; cs < 2; ++cs) {
                    int off = xrow + 0 * 64 + cs * 32 + l4 * 8;
                    xbh[0][cs] = *(const us8*)(xh + off);
                    xbl[0][cs] = *(const us8*)(xl + off);
                }
            }
            if (j < 7) {
#pragma unroll
                for (int cs = 0; cs < 2; ++cs) {
                    int off = xrow + (j + 1) * 64 + cs * 32 + l4 * 8;
                    xbh[(j + 1) & 1][cs] = *(const us8*)(xh + off);
                    xbl[(j + 1) & 1][cs] = *(const us8*)(xl + off);
                }
            }
            // stage 2 phases ahead into buf[(cur+2)%3]
            {
                char* d = smem + ((cur + 2) % 3) * 32768 + stg;
                if (j < 6) {            // A chunk j+2 (hi+lo, 32 KB)
                    const char* s = imgA + ((size_t)gt * 8 + j + 2) * 32768;
#pragma unroll
                    for (int i = 0; i < 4; ++i) gload16(s + stg + i * 8192, d + i * 8192);
                } else if (j == 6) {    // C chunk 0 (hi-only, 16 KB)
                    const char* s = imgC + ((size_t)gt * 8 + 0) * 32768;
#pragma unroll
                    for (int i = 0; i < 2; ++i) gload16(s + stg + i * 8192, d + i * 8192);
                } else {                // j==7: C chunk 1 (hi-only)
                    const char* s = imgC + ((size_t)gt * 8 + 1) * 32768;
#pragma unroll
                    for (int i = 0; i < 2; ++i) gload16(s + stg + i * 8192, d + i * 8192);
                }
            }
            // MFMA on current buffer
            const char* B = smem + cur * 32768;
#pragma unroll
            for (int cs = 0; cs < 2; ++cs) {
#pragma unroll
                for (int f = 0; f < 4; ++f) {
                    int row = wc * 64 + f * 16 + l15;              // k-index in tile
                    int byte = row * 128 + ((cs * 64 + l4 * 16) ^ ((row & 7) << 4));
                    bfv8 qh = *(const bfv8*)(B + byte);
                    bfv8 ql = *(const bfv8*)(B + 16384 + byte);
                    sf[f] = MFMA16(BC(xbh[j & 1][cs]), qh, sf[f]);
                    sf[f] = MFMA16(BC(xbh[j & 1][cs]), ql, sf[f]);
                    sf[f] = MFMA16(BC(xbl[j & 1][cs]), qh, sf[f]);
                }
            }
            // counted barrier: N = vmem items issued THIS phase
            if (j == 0)      PHASE_BAR(8);   // xcold2 + xpref2 + stage4
            else if (j < 6)  PHASE_BAR(6);   // xpref2 + stage4
            else if (j == 6) PHASE_BAR(4);   // xpref2 + stage2
            else             PHASE_BAR(2);   // stage2
            cur = (cur + 1) % 3;
        }

        // ---------- Phase B: online softmax (__syncthreads drains C0/C1) ----------
        float g[4][4];
#pragma unroll
        for (int f = 0; f < 4; ++f) {
            float asq = Asq[kbase + wc * 64 + f * 16 + l15];
#pragma unroll
            for (int q = 0; q < 4; ++q) g[f][q] = sa[q] * sf[f][q] - hb[q] * asq;
        }
        float tmax[4];
#pragma unroll
        for (int q = 0; q < 4; ++q)
            tmax[q] = fmaxf(fmaxf(g[0][q], g[1][q]), fmaxf(g[2][q], g[3][q]));
#pragma unroll
        for (int off = 1; off < 16; off <<= 1)
#pragma unroll
            for (int q = 0; q < 4; ++q) tmax[q] = fmaxf(tmax[q], __shfl_xor(tmax[q], off));
        float* smax = (float*)(smem + SM_MX);
        if (l15 == 0) {
#pragma unroll
            for (int q = 0; q < 4; ++q) smax[wc * 64 + wr * 16 + l4 * 4 + q] = tmax[q];
        }
        __syncthreads();
        float Mn[4], al[4];
#pragma unroll
        for (int q = 0; q < 4; ++q) {
            float other = smax[(wc ^ 1) * 64 + wr * 16 + l4 * 4 + q];
            float tm = fmaxf(tmax[q], other);
            Mn[q] = fmaxf(Mr[q], tm);
            al[q] = exp2f((Mr[q] - Mn[q]) * ce[q]);
        }
        float u[4][4], tsum[4] = {0.f, 0.f, 0.f, 0.f};
#pragma unroll
        for (int f = 0; f < 4; ++f)
#pragma unroll
            for (int q = 0; q < 4; ++q) {
                u[f][q] = exp2f((g[f][q] - Mn[q]) * ce[q]);
                tsum[q] += u[f][q];
            }
#pragma unroll
        for (int off = 1; off < 16; off <<= 1)
#pragma unroll
            for (int q = 0; q < 4; ++q) tsum[q] += __shfl_xor(tsum[q], off);
        float* ssum = (float*)(smem + SM_SM);
        if (l15 == 0) {
#pragma unroll
            for (int q = 0; q < 4; ++q) ssum[wc * 64 + wr * 16 + l4 * 4 + q] = tsum[q];
        }
        // write u (bf16 hi/lo) to LDS for GEMM2 A-operand
#pragma unroll
        for (int f = 0; f < 4; ++f)
#pragma unroll
            for (int q = 0; q < 4; ++q) {
                int m_loc = wr * 16 + l4 * 4 + q;
                int k_loc = wc * 64 + f * 16 + l15;
                int byte = (m_loc * 256 + k_loc * 2) ^ ((m_loc & 7) << 4);
                unsigned short uh = f2bf(u[f][q]);
                *(unsigned short*)(smem + SM_U + byte) = uh;
                *(unsigned short*)(smem + SM_U2 + byte) = f2bf(u[f][q] - bf2f(uh));
            }
        __syncthreads();
#pragma unroll
        for (int q = 0; q < 4; ++q) {
            float others = ssum[(wc ^ 1) * 64 + wr * 16 + l4 * 4 + q];
            Lr[q] = Lr[q] * al[q] + tsum[q] + others;
            Mr[q] = Mn[q];
        }
#pragma unroll
        for (int a = 0; a < 8; ++a)
#pragma unroll
            for (int b = 0; b < 2; ++b)
#pragma unroll
                for (int q = 0; q < 4; ++q) of[a][b][q] *= al[q];

        // ---------- Phase C: O[64m][512c] += (uh+ul) * Ah_tile, 8 chunks of 64 c ----------
        us8 uhf[4], ulf[4];
#pragma unroll
        for (int ks = 0; ks < 4; ++ks) {
            int m_loc = wr * 16 + l15;
            int byte = (m_loc * 256 + ks * 64 + l4 * 16) ^ ((m_loc & 7) << 4);
            uhf[ks] = *(const us8*)(smem + SM_U + byte);
            ulf[ks] = *(const us8*)(smem + SM_U2 + byte);
        }
#pragma unroll
        for (int j = 0; j < 8; ++j) {
            // stage 2 phases ahead
            {
                char* d = smem + ((cur + 2) % 3) * 32768 + stg;
                if (j < 6) {            // C chunk j+2 (hi-only)
                    const char* s = imgC + ((size_t)gt * 8 + j + 2) * 32768;
#pragma unroll
                    for (int i = 0; i < 2; ++i) gload16(s + stg + i * 8192, d + i * 8192);
                } else {                // j==6/7: next tile A chunk 0/1 (wrapped last tile)
                    const char* s = imgA + ((size_t)gtn * 8 + (j - 6)) * 32768;
#pragma unroll
                    for (int i = 0; i < 4; ++i) gload16(s + stg + i * 8192, d + i * 8192);
                }
            }
            const char* B = smem + cur * 32768;
#pragma unroll
            for (int f = 0; f < 2; ++f) {
                int cl = wc * 32 + f * 16 + l15;                   // c-row in chunk
#pragma unroll
                for (int ks = 0; ks < 4; ++ks) {
                    int byte = cl * 256 + ((ks * 64 + l4 * 16) ^ ((cl & 7) << 4));
                    bfv8 qh = *(const bfv8*)(B + byte);
                    of[j][f] = MFMA16(BC(uhf[ks]), qh, of[j][f]);
                    of[j][f] = MFMA16(BC(ulf[ks]), qh, of[j][f]);
                }
            }
            if (j < 6) PHASE_BAR(2);     // stage2
            else       PHASE_BAR(4);     // stage4
            cur = (cur + 1) % 3;
        }
    }

    // ---------- write split partials ----------
#pragma unroll
    for (int j = 0; j < 8; ++j)
#pragma unroll
        for (int f = 0; f < 2; ++f)
#pragma unroll
            for (int q = 0; q < 4; ++q) {
                int gm = rb + wr * 16 + l4 * 4 + q;
                int cg = j * 64 + wc * 32 + f * 16 + l15;
                pO[((size_t)gm * SPLITS + split) * C_DIM + cg] = of[j][f][q];
            }
    if (wc == 0 && l15 == 0) {
#pragma unroll
        for (int q = 0; q < 4; ++q) {
            int gm = rb + wr * 16 + l4 * 4 + q;
            pM[gm * SPLITS + split] = Mr[q];
            pL[gm * SPLITS + split] = Lr[q];
        }
    }
}

// ======================= split-K combine =======================
__global__ void k_combine(const float* __restrict__ pO, const float* __restrict__ pM,
                          const float* __restrict__ pL, const float4* __restrict__ rowp,
                          float* __restrict__ out) {
    int r = blockIdx.x;
    int tid = threadIdx.x;   // 128 threads, 4 c's each
    float ce = rowp[r].z;
    float Ms[SPLITS], Ls[SPLITS];
    float M = -1e30f;
#pragma unroll
    for (int s = 0; s < SPLITS; ++s) {
        Ms[s] = pM[r * SPLITS + s];
        Ls[s] = pL[r * SPLITS + s];
        M = fmaxf(M, Ms[s]);
    }
    float es[SPLITS], L = 0.f;
#pragma unroll
    for (int s = 0; s < SPLITS; ++s) { es[s] = exp2f((Ms[s] - M) * ce); L += Ls[s] * es[s]; }
    float invL = 1.0f / L;
    f32x4 acc = (f32x4){0.f, 0.f, 0.f, 0.f};
#pragma unroll
    for (int s = 0; s < SPLITS; ++s) {
        f32x4 v = *(const f32x4*)(pO + ((size_t)r * SPLITS + s) * C_DIM + tid * 4);
        acc += v * es[s];
    }
    acc *= invL;
    *(f32x4*)(out + (size_t)r * C_DIM + tid * 4) = acc;
}

// ======================= launch =======================
extern "C" void kernel_launch(void* const* d_in, const int* in_sizes, int n_in,
                              void* d_out, int out_size, void* d_ws, size_t ws_size,
                              hipStream_t stream) {
    const float* x = (const float*)d_in[0];
    const int* t = (const int*)d_in[1];
    const float* A = (const float*)d_in[2];
    const float* bar_alpha = (const float*)d_in[3];
    float* out = (float*)d_out;
    char* ws = (char*)d_ws;
    if (ws_size < WS_NEED) return;

    char* imgA = ws + OFF_IMGA;
    char* imgC = ws + OFF_IMGC;
    unsigned short* Xh = (unsigned short*)(ws + OFF_XH);
    unsigned short* Xl = (unsigned short*)(ws + OFF_XL);
    float* Asq = (float*)(ws + OFF_ASQ);
    float4* rowp = (float4*)(ws + OFF_ROWP);
    float* pO = (float*)(ws + OFF_PO);
    float* pM = (float*)(ws + OFF_PM);
    float* pL = (float*)(ws + OFF_PL);

    (void)hipFuncSetAttribute((const void*)k_fused,
                              hipFuncAttributeMaxDynamicSharedMemorySize, SM_TOT);

    k_rows<<<R_DIM / 256, 256, 0, stream>>>(t, bar_alpha, rowp);
    k_splitx<<<(R_DIM * C_DIM / 8) / 256, 256, 0, stream>>>(x, (us8*)Xh, (us8*)Xl);
    k_imgA<<<GTILES * 8, 256, 0, stream>>>(A, imgA);
    k_imgC<<<GTILES * 8, 256, 0, stream>>>(A, imgC);
    k_asq<<<K_DIM / 4, 256, 0, stream>>>(A, Asq);
    k_fused<<<(R_DIM / BM) * SPLITS, 512, SM_TOT, stream>>>(imgA, imgC, Xh, Xl,
                                                            Asq, rowp, pO, pM, pL);
    k_combine<<<R_DIM, 128, 0, stream>>>(pO, pM, pL, rowp, out);
}